// Round 5
// baseline (506.291 us; speedup 1.0000x reference)
//
#include <hip/hip_runtime.h>
#include <cstdint>
#include <cstddef>

#define U_NODES 100000
#define V_NODES 50000
#define N_EDGES 2000000

// dims: F=32 (u), G=32 (v), H=8 (edge); g: 72->64->32 ; f: 64->64->32 ; tail 32->1
// g_w1 rows: [0,32) u-part, [32,64) v-part, [64,72) edge-val part.

__device__ __forceinline__ void load8f(const float* __restrict__ p, float* x) {
    const float4* p4 = reinterpret_cast<const float4*>(p);
    float4 a = p4[0], b = p4[1];
    x[0]=a.x; x[1]=a.y; x[2]=a.z; x[3]=a.w;
    x[4]=b.x; x[5]=b.y; x[6]=b.z; x[7]=b.w;
}

__device__ __forceinline__ void load32f(const float* __restrict__ p, float* x) {
    #pragma unroll
    for (int q = 0; q < 4; ++q) load8f(p + 8*q, x + 8*q);
}

// RNE round two f32 to bf16, packed low|high
__device__ __forceinline__ unsigned pack_bf16x2(float a, float b) {
    unsigned ua = __float_as_uint(a);
    ua = (ua + 0x7FFFu + ((ua >> 16) & 1u)) >> 16;
    unsigned ub = __float_as_uint(b);
    ub = (ub + 0x7FFFu + ((ub >> 16) & 1u)) & 0xFFFF0000u;
    return ua | ub;
}

// ---------------- pre-projection (A = u@W1u ; B = v@W1v + b1) ------------------

__global__ __launch_bounds__(256) void proj_u_kernel(
    const float* __restrict__ u, const float* __restrict__ g_w1,
    float* __restrict__ A)
{
    int n = blockIdx.x * 256 + threadIdx.x;
    if (n >= U_NODES) return;
    float x[32];
    load32f(u + (size_t)n * 32, x);
    float acc[64];
    #pragma unroll
    for (int j = 0; j < 64; ++j) acc[j] = 0.f;
    #pragma unroll
    for (int i = 0; i < 32; ++i) {
        #pragma unroll
        for (int j = 0; j < 64; ++j) acc[j] += x[i] * g_w1[i*64 + j];
    }
    float4* Ap = reinterpret_cast<float4*>(A + (size_t)n * 64);
    #pragma unroll
    for (int q = 0; q < 16; ++q)
        Ap[q] = make_float4(acc[4*q], acc[4*q+1], acc[4*q+2], acc[4*q+3]);
}

__global__ __launch_bounds__(256) void proj_v_kernel(
    const float* __restrict__ v, const float* __restrict__ g_w1,
    const float* __restrict__ g_b1, float* __restrict__ B)
{
    int n = blockIdx.x * 256 + threadIdx.x;
    if (n >= V_NODES) return;
    float x[32];
    load32f(v + (size_t)n * 32, x);
    float acc[64];
    #pragma unroll
    for (int j = 0; j < 64; ++j) acc[j] = g_b1[j];
    #pragma unroll
    for (int i = 0; i < 32; ++i) {
        #pragma unroll
        for (int j = 0; j < 64; ++j) acc[j] += x[i] * g_w1[(32+i)*64 + j];
    }
    float4* Bp = reinterpret_cast<float4*>(B + (size_t)n * 64);
    #pragma unroll
    for (int q = 0; q < 16; ++q)
        Bp[q] = make_float4(acc[4*q], acc[4*q+1], acc[4*q+2], acc[4*q+3]);
}

// ---------------- CSR build ----------------------------------------------------

__global__ __launch_bounds__(256) void rank_kernel(
    const int* __restrict__ e_dst, int* __restrict__ deg, int* __restrict__ rank)
{
    int e = blockIdx.x * 256 + threadIdx.x;
    if (e >= N_EDGES) return;
    rank[e] = atomicAdd(&deg[e_dst[e]], 1);
}

__global__ __launch_bounds__(256) void scan_block_kernel(
    const int* __restrict__ deg, int* __restrict__ off, int* __restrict__ aux, int n)
{
    __shared__ int s[256];
    int tid = threadIdx.x;
    int i = blockIdx.x * 256 + tid;
    int x = (i < n) ? deg[i] : 0;
    s[tid] = x;
    __syncthreads();
    #pragma unroll
    for (int o = 1; o < 256; o <<= 1) {
        int t = (tid >= o) ? s[tid - o] : 0;
        __syncthreads();
        s[tid] += t;
        __syncthreads();
    }
    if (i < n) off[i + 1] = s[tid];
    if (tid == 255) aux[blockIdx.x] = s[255];
}

__global__ __launch_bounds__(512) void scan_aux_kernel(int* __restrict__ aux, int nA)
{
    __shared__ int s[512];
    int tid = threadIdx.x;
    int x = (tid < nA) ? aux[tid] : 0;
    s[tid] = x;
    __syncthreads();
    #pragma unroll
    for (int o = 1; o < 512; o <<= 1) {
        int t = (tid >= o) ? s[tid - o] : 0;
        __syncthreads();
        s[tid] += t;
        __syncthreads();
    }
    if (tid < nA) aux[tid] = s[tid] - x;  // exclusive
}

__global__ __launch_bounds__(256) void scan_add_kernel(
    int* __restrict__ off, const int* __restrict__ aux, int n)
{
    int i = blockIdx.x * 256 + threadIdx.x;
    if (i == 0) off[0] = 0;
    if (i < n) off[i + 1] += aux[i >> 8];
}

// scatter edge id only (fallback path)
__global__ __launch_bounds__(256) void scatter_kernel(
    const int* __restrict__ e_dst, const int* __restrict__ off,
    const int* __restrict__ rank, int* __restrict__ sorted_eid)
{
    int e = blockIdx.x * 256 + threadIdx.x;
    if (e >= N_EDGES) return;
    int d = e_dst[e];
    sorted_eid[off[d] + rank[e]] = e;
}

// full payload permutation into destination-sorted order (coalesced reads)
__global__ __launch_bounds__(256) void permute_kernel(
    const int* __restrict__ e_dst, const int* __restrict__ e_src,
    const int* __restrict__ rank, const int* __restrict__ off,
    const float* __restrict__ e_vals,
    int* __restrict__ d_sorted, int* __restrict__ s_sorted,
    float* __restrict__ ev_sorted)
{
    int e = blockIdx.x * 256 + threadIdx.x;
    if (e >= N_EDGES) return;
    int d = e_dst[e];
    int pos = off[d] + rank[e];
    d_sorted[pos] = d;
    s_sorted[pos] = e_src[e];
    const float4* src = reinterpret_cast<const float4*>(e_vals + (size_t)e * 8);
    float4 v0 = src[0], v1 = src[1];
    float4* dst = reinterpret_cast<float4*>(ev_sorted + (size_t)pos * 8);
    dst[0] = v0; dst[1] = v1;
}

// ------ edge MLP over permuted (fully coalesced) streams + LDS segmented reduce -
// HAS_A: A[d] precomputed; otherwise compute u-part from u[d] (grouped access).
// B always present on this path (includes bias g_b1).

template <bool HAS_A>
__global__ __launch_bounds__(256) void edge_perm_kernel(
    const float* __restrict__ A, const float* __restrict__ B,
    const float* __restrict__ u,
    const int* __restrict__ d_sorted, const int* __restrict__ s_sorted,
    const float* __restrict__ ev_sorted,
    const float* __restrict__ g_w1, const float* __restrict__ g_w2,
    const float* __restrict__ g_b2, float* __restrict__ agg)
{
    __shared__ unsigned lds_h[256][17];  // 16 packed bf16x2 words + 1 pad
    __shared__ int lds_d[256];
    __shared__ int lds_heads[256];       // tid | (true_head << 16)
    __shared__ int lds_cnt;
    __shared__ int lds_prev_d, lds_next_d;

    const int tid = threadIdx.x;
    const long p = (long)blockIdx.x * 256 + tid;

    if (tid == 0) {
        lds_cnt = 0;
        long pprev = (long)blockIdx.x * 256 - 1;
        lds_prev_d = (pprev < 0) ? -2 : d_sorted[pprev];
        long pnext = (long)blockIdx.x * 256 + 256;
        lds_next_d = (pnext >= N_EDGES) ? -2 : d_sorted[pnext];
    }

    int d = -1;
    if (p < N_EDGES) {
        d = d_sorted[p];
        int s = s_sorted[p];

        float h1[64];
        if constexpr (HAS_A) {
            const float4* Ap = reinterpret_cast<const float4*>(A + (size_t)d * 64);
            #pragma unroll
            for (int q = 0; q < 16; ++q) {
                float4 a = Ap[q];
                h1[4*q+0] = a.x; h1[4*q+1] = a.y; h1[4*q+2] = a.z; h1[4*q+3] = a.w;
            }
        } else {
            #pragma unroll
            for (int j = 0; j < 64; ++j) h1[j] = 0.f;
            float x[32];
            load32f(u + (size_t)d * 32, x);
            #pragma unroll
            for (int i = 0; i < 32; ++i) {
                #pragma unroll
                for (int j = 0; j < 64; ++j) h1[j] += x[i] * g_w1[i*64 + j];
            }
        }
        {
            const float4* Bp = reinterpret_cast<const float4*>(B + (size_t)s * 64);
            #pragma unroll
            for (int q = 0; q < 16; ++q) {
                float4 b = Bp[q];
                h1[4*q+0] += b.x; h1[4*q+1] += b.y; h1[4*q+2] += b.z; h1[4*q+3] += b.w;
            }
        }
        float ev[8];
        load8f(ev_sorted + (size_t)p * 8, ev);
        #pragma unroll
        for (int i = 0; i < 8; ++i) {
            #pragma unroll
            for (int j = 0; j < 64; ++j) h1[j] += ev[i] * g_w1[(64+i)*64 + j];
        }
        #pragma unroll
        for (int j = 0; j < 64; ++j) h1[j] = fmaxf(h1[j], 0.f);

        float h2[32];
        #pragma unroll
        for (int k = 0; k < 32; ++k) h2[k] = g_b2[k];
        #pragma unroll
        for (int i = 0; i < 64; ++i) {
            #pragma unroll
            for (int k = 0; k < 32; ++k) h2[k] += h1[i] * g_w2[i*32 + k];
        }
        #pragma unroll
        for (int cp = 0; cp < 16; ++cp)
            lds_h[tid][cp] = pack_bf16x2(fmaxf(h2[2*cp], 0.f), fmaxf(h2[2*cp+1], 0.f));
    }
    lds_d[tid] = d;
    __syncthreads();

    if (p < N_EDGES) {
        int prevd = (tid == 0) ? lds_prev_d : lds_d[tid - 1];
        bool true_head = (prevd != d);
        bool is_head = (tid == 0) || true_head;
        if (is_head) {
            int idx = atomicAdd(&lds_cnt, 1);
            lds_heads[idx] = tid | (true_head ? 0x10000 : 0);
        }
    }
    __syncthreads();

    const int nseg = lds_cnt;
    const int next_d = lds_next_d;
    for (int w = tid; w < nseg * 16; w += 256) {
        int seg = w >> 4, cp = w & 15;
        int ent = lds_heads[seg];
        int h = ent & 0xFFFF;
        bool thead = (ent & 0x10000) != 0;
        int dd = lds_d[h];
        float s0 = 0.f, s1 = 0.f;
        int r = h;
        while (r < 256 && lds_d[r] == dd) {
            unsigned x = lds_h[r][cp];
            s0 += __uint_as_float(x << 16);
            s1 += __uint_as_float(x & 0xFFFF0000u);
            ++r;
        }
        bool end_complete = (r < 256) || (next_d != dd);
        float* dst = agg + (size_t)dd * 32 + 2 * cp;
        if (thead && end_complete) {
            *reinterpret_cast<float2*>(dst) = make_float2(s0, s1);  // sole writer
        } else {
            atomicAdd(dst + 0, s0);
            atomicAdd(dst + 1, s1);
        }
    }
}

// ------- fallback: edge MLP via seid gathers (round-4 proven path) --------------

template <bool HAS_A, bool HAS_B>
__global__ __launch_bounds__(256) void edge_sorted_kernel(
    const float* __restrict__ A, const float* __restrict__ B,
    const float* __restrict__ u, const float* __restrict__ v,
    const float* __restrict__ e_vals, const int* __restrict__ e_src,
    const int* __restrict__ e_dst, const int* __restrict__ seid,
    const float* __restrict__ g_w1, const float* __restrict__ g_b1,
    const float* __restrict__ g_w2, const float* __restrict__ g_b2,
    float* __restrict__ agg)
{
    __shared__ unsigned lds_h[256][17];
    __shared__ int lds_d[256];
    __shared__ int lds_heads[256];
    __shared__ int lds_cnt;
    __shared__ int lds_prev_d, lds_next_d;

    const int tid = threadIdx.x;
    const long p = (long)blockIdx.x * 256 + tid;

    if (tid == 0) {
        lds_cnt = 0;
        long pprev = (long)blockIdx.x * 256 - 1;
        lds_prev_d = (pprev < 0) ? -2 : e_dst[seid[pprev]];
        long pnext = (long)blockIdx.x * 256 + 256;
        lds_next_d = (pnext >= N_EDGES) ? -2 : e_dst[seid[pnext]];
    }

    int d = -1;
    if (p < N_EDGES) {
        int eid = seid[p];
        d = e_dst[eid];
        int s = e_src[eid];

        float h1[64];
        if constexpr (HAS_A) {
            const float4* Ap = reinterpret_cast<const float4*>(A + (size_t)d * 64);
            #pragma unroll
            for (int q = 0; q < 16; ++q) {
                float4 a = Ap[q];
                h1[4*q+0] = a.x; h1[4*q+1] = a.y; h1[4*q+2] = a.z; h1[4*q+3] = a.w;
            }
        } else {
            #pragma unroll
            for (int j = 0; j < 64; ++j) h1[j] = 0.f;
            float x[32];
            load32f(u + (size_t)d * 32, x);
            #pragma unroll
            for (int i = 0; i < 32; ++i) {
                #pragma unroll
                for (int j = 0; j < 64; ++j) h1[j] += x[i] * g_w1[i*64 + j];
            }
        }
        if constexpr (HAS_B) {
            const float4* Bp = reinterpret_cast<const float4*>(B + (size_t)s * 64);
            #pragma unroll
            for (int q = 0; q < 16; ++q) {
                float4 b = Bp[q];
                h1[4*q+0] += b.x; h1[4*q+1] += b.y; h1[4*q+2] += b.z; h1[4*q+3] += b.w;
            }
        } else {
            #pragma unroll
            for (int j = 0; j < 64; ++j) h1[j] += g_b1[j];
            float x[32];
            load32f(v + (size_t)s * 32, x);
            #pragma unroll
            for (int i = 0; i < 32; ++i) {
                #pragma unroll
                for (int j = 0; j < 64; ++j) h1[j] += x[i] * g_w1[(32+i)*64 + j];
            }
        }
        float ev[8];
        load8f(e_vals + (size_t)eid * 8, ev);
        #pragma unroll
        for (int i = 0; i < 8; ++i) {
            #pragma unroll
            for (int j = 0; j < 64; ++j) h1[j] += ev[i] * g_w1[(64+i)*64 + j];
        }
        #pragma unroll
        for (int j = 0; j < 64; ++j) h1[j] = fmaxf(h1[j], 0.f);

        float h2[32];
        #pragma unroll
        for (int k = 0; k < 32; ++k) h2[k] = g_b2[k];
        #pragma unroll
        for (int i = 0; i < 64; ++i) {
            #pragma unroll
            for (int k = 0; k < 32; ++k) h2[k] += h1[i] * g_w2[i*32 + k];
        }
        #pragma unroll
        for (int cp = 0; cp < 16; ++cp)
            lds_h[tid][cp] = pack_bf16x2(fmaxf(h2[2*cp], 0.f), fmaxf(h2[2*cp+1], 0.f));
    }
    lds_d[tid] = d;
    __syncthreads();

    if (p < N_EDGES) {
        int prevd = (tid == 0) ? lds_prev_d : lds_d[tid - 1];
        bool true_head = (prevd != d);
        bool is_head = (tid == 0) || true_head;
        if (is_head) {
            int idx = atomicAdd(&lds_cnt, 1);
            lds_heads[idx] = tid | (true_head ? 0x10000 : 0);
        }
    }
    __syncthreads();

    const int nseg = lds_cnt;
    const int next_d = lds_next_d;
    for (int w = tid; w < nseg * 16; w += 256) {
        int seg = w >> 4, cp = w & 15;
        int ent = lds_heads[seg];
        int h = ent & 0xFFFF;
        bool thead = (ent & 0x10000) != 0;
        int dd = lds_d[h];
        float s0 = 0.f, s1 = 0.f;
        int r = h;
        while (r < 256 && lds_d[r] == dd) {
            unsigned x = lds_h[r][cp];
            s0 += __uint_as_float(x << 16);
            s1 += __uint_as_float(x & 0xFFFF0000u);
            ++r;
        }
        bool end_complete = (r < 256) || (next_d != dd);
        float* dst = agg + (size_t)dd * 32 + 2 * cp;
        if (thead && end_complete) {
            *reinterpret_cast<float2*>(dst) = make_float2(s0, s1);
        } else {
            atomicAdd(dst + 0, s0);
            atomicAdd(dst + 1, s1);
        }
    }
}

// ---------------- node MLP (reads agg) -----------------------------------------

__global__ __launch_bounds__(256) void node_kernel(
    const float* __restrict__ u, const float* __restrict__ agg,
    const float* __restrict__ f_w1, const float* __restrict__ f_b1,
    const float* __restrict__ f_w2, const float* __restrict__ f_b2,
    const float* __restrict__ t_w, const float* __restrict__ t_b,
    float* __restrict__ out)
{
    int n = blockIdx.x * 256 + threadIdx.x;
    if (n >= U_NODES) return;
    float x[64];
    load32f(u   + (size_t)n * 32, x);
    load32f(agg + (size_t)n * 32, x + 32);
    float z1[64];
    #pragma unroll
    for (int j = 0; j < 64; ++j) z1[j] = f_b1[j];
    #pragma unroll
    for (int i = 0; i < 64; ++i) {
        #pragma unroll
        for (int j = 0; j < 64; ++j) z1[j] += x[i] * f_w1[i*64 + j];
    }
    #pragma unroll
    for (int j = 0; j < 64; ++j) z1[j] = fmaxf(z1[j], 0.f);
    float z2[32];
    #pragma unroll
    for (int k = 0; k < 32; ++k) z2[k] = f_b2[k];
    #pragma unroll
    for (int j = 0; j < 64; ++j) {
        #pragma unroll
        for (int k = 0; k < 32; ++k) z2[k] += z1[j] * f_w2[j*32 + k];
    }
    #pragma unroll
    for (int k = 0; k < 32; ++k) z2[k] = fmaxf(z2[k], 0.f);
    float o = t_b[0];
    #pragma unroll
    for (int k = 0; k < 32; ++k) o += z2[k] * t_w[k];
    out[n] = 1.f / (1.f + expf(-o));
}

// ---------------- last-resort atomic fallback -----------------------------------

__global__ __launch_bounds__(256) void edge_direct_kernel(
    const float* __restrict__ u, const float* __restrict__ v,
    const float* __restrict__ e_vals, const int* __restrict__ e_src,
    const int* __restrict__ e_dst, const float* __restrict__ g_w1,
    const float* __restrict__ g_b1, const float* __restrict__ g_w2,
    const float* __restrict__ g_b2, float* __restrict__ agg)
{
    int e = blockIdx.x * 256 + threadIdx.x;
    if (e >= N_EDGES) return;
    int d = e_dst[e];
    int s = e_src[e];
    float x[72];
    load32f(u + (size_t)d * 32, x);
    load32f(v + (size_t)s * 32, x + 32);
    load8f(e_vals + (size_t)e * 8, x + 64);
    float h1[64];
    #pragma unroll
    for (int j = 0; j < 64; ++j) h1[j] = g_b1[j];
    #pragma unroll
    for (int i = 0; i < 72; ++i) {
        #pragma unroll
        for (int j = 0; j < 64; ++j) h1[j] += x[i] * g_w1[i*64 + j];
    }
    #pragma unroll
    for (int j = 0; j < 64; ++j) h1[j] = fmaxf(h1[j], 0.f);
    float acc2[32];
    #pragma unroll
    for (int k = 0; k < 32; ++k) acc2[k] = g_b2[k];
    #pragma unroll
    for (int i = 0; i < 64; ++i) {
        #pragma unroll
        for (int k = 0; k < 32; ++k) acc2[k] += h1[i] * g_w2[i*32 + k];
    }
    float* aggp = agg + (size_t)d * 32;
    #pragma unroll
    for (int k = 0; k < 32; ++k) atomicAdd(aggp + k, fmaxf(acc2[k], 0.f));
}

// ---------------- launch -------------------------------------------------------

static inline size_t align256(size_t x) { return (x + 255) & ~(size_t)255; }

extern "C" void kernel_launch(void* const* d_in, const int* in_sizes, int n_in,
                              void* d_out, int out_size, void* d_ws, size_t ws_size,
                              hipStream_t stream) {
    const float* u      = (const float*)d_in[0];
    const float* v      = (const float*)d_in[1];
    const float* e_vals = (const float*)d_in[2];
    const int*   e_src  = (const int*)  d_in[3];
    const int*   e_dst  = (const int*)  d_in[4];
    const float* g_w1   = (const float*)d_in[5];
    const float* g_b1   = (const float*)d_in[6];
    const float* g_w2   = (const float*)d_in[7];
    const float* g_b2   = (const float*)d_in[8];
    const float* f_w1   = (const float*)d_in[9];
    const float* f_b1   = (const float*)d_in[10];
    const float* f_w2   = (const float*)d_in[11];
    const float* f_b2   = (const float*)d_in[12];
    const float* t_w    = (const float*)d_in[13];
    const float* t_b    = (const float*)d_in[14];
    float* out = (float*)d_out;

    char* wsc = (char*)d_ws;
    const int nChunks = (U_NODES + 255) / 256;                    // 391
    const int eBlocks = (N_EDGES + 255) / 256;

    const size_t degB  = align256((size_t)U_NODES * 4);
    const size_t offB  = align256((size_t)(U_NODES + 1) * 4);
    const size_t auxB  = align256((size_t)nChunks * 4);
    const size_t aggB  = align256((size_t)U_NODES * 32 * 4);      // 12.8 MB
    const size_t e4B   = align256((size_t)N_EDGES * 4);           // 8 MB
    const size_t evB   = align256((size_t)N_EDGES * 32);          // 64 MB
    const size_t bB    = align256((size_t)V_NODES * 64 * 4);      // 12.8 MB
    const size_t aB    = align256((size_t)U_NODES * 64 * 4);      // 25.6 MB

    size_t o = 0;
    size_t oDeg = o; o += degB;
    size_t oOff = o; o += offB;
    size_t oAux = o; o += auxB;
    size_t oAgg = o; o += aggB;
    size_t baseNeed = o;                                          // ~13.7 MB

    // new permuted-path layout
    size_t oDs = o;  o += e4B;
    size_t oSs = o;  o += e4B;
    size_t oEv = o;  o += evB;
    size_t oBn = o;  o += bB;
    size_t needT2 = o;                 // ~107 MB ; rank aliases B (proj_v after permute)
    size_t oAn = o;  o += aB;
    size_t needT1 = o;                 // ~132 MB ; rank aliases A (proj_u after permute)

    // fallback (round-4) layout
    size_t o3 = baseNeed;
    size_t oSeid = o3; o3 += e4B;
    size_t needT4 = o3 + e4B;          // <false,false> : rank after seid (~29.7 MB)
    size_t oB3 = o3;   o3 += bB;
    size_t oA3 = o3;   o3 += aB;
    size_t needT3 = o3;                // ~60 MB ; rank aliases A3

    int* deg   = (int*)(wsc + oDeg);
    int* off   = (int*)(wsc + oOff);
    int* aux   = (int*)(wsc + oAux);
    float* agg = (float*)(wsc + oAgg);

    if (ws_size >= needT2) {
        const bool hasA = (ws_size >= needT1);
        int* ds    = (int*)(wsc + oDs);
        int* ss    = (int*)(wsc + oSs);
        float* evs = (float*)(wsc + oEv);
        float* B   = (float*)(wsc + oBn);
        float* A   = hasA ? (float*)(wsc + oAn) : nullptr;
        int* rank  = hasA ? (int*)A : (int*)B;   // aliased; written after permute

        hipMemsetAsync(deg, 0, (size_t)U_NODES * 4, stream);
        hipMemsetAsync(agg, 0, (size_t)U_NODES * 32 * 4, stream);

        rank_kernel<<<eBlocks, 256, 0, stream>>>(e_dst, deg, rank);
        scan_block_kernel<<<nChunks, 256, 0, stream>>>(deg, off, aux, U_NODES);
        scan_aux_kernel<<<1, 512, 0, stream>>>(aux, nChunks);
        scan_add_kernel<<<nChunks, 256, 0, stream>>>(off, aux, U_NODES);
        permute_kernel<<<eBlocks, 256, 0, stream>>>(e_dst, e_src, rank, off, e_vals,
                                                    ds, ss, evs);
        proj_v_kernel<<<(V_NODES + 255) / 256, 256, 0, stream>>>(v, g_w1, g_b1, B);
        if (hasA) {
            proj_u_kernel<<<(U_NODES + 255) / 256, 256, 0, stream>>>(u, g_w1, A);
            edge_perm_kernel<true><<<eBlocks, 256, 0, stream>>>(
                A, B, u, ds, ss, evs, g_w1, g_w2, g_b2, agg);
        } else {
            edge_perm_kernel<false><<<eBlocks, 256, 0, stream>>>(
                nullptr, B, u, ds, ss, evs, g_w1, g_w2, g_b2, agg);
        }
        node_kernel<<<(U_NODES + 255) / 256, 256, 0, stream>>>(
            u, agg, f_w1, f_b1, f_w2, f_b2, t_w, t_b, out);
    } else if (ws_size >= needT4) {
        const bool hasAB = (ws_size >= needT3);
        int* seid = (int*)(wsc + oSeid);
        float* B = hasAB ? (float*)(wsc + oB3) : nullptr;
        float* A = hasAB ? (float*)(wsc + oA3) : nullptr;
        int* rank = hasAB ? (int*)A : (int*)(wsc + oSeid + e4B);

        hipMemsetAsync(deg, 0, (size_t)U_NODES * 4, stream);
        hipMemsetAsync(agg, 0, (size_t)U_NODES * 32 * 4, stream);

        rank_kernel<<<eBlocks, 256, 0, stream>>>(e_dst, deg, rank);
        scan_block_kernel<<<nChunks, 256, 0, stream>>>(deg, off, aux, U_NODES);
        scan_aux_kernel<<<1, 512, 0, stream>>>(aux, nChunks);
        scan_add_kernel<<<nChunks, 256, 0, stream>>>(off, aux, U_NODES);
        scatter_kernel<<<eBlocks, 256, 0, stream>>>(e_dst, off, rank, seid);

        if (hasAB) {
            proj_v_kernel<<<(V_NODES + 255) / 256, 256, 0, stream>>>(v, g_w1, g_b1, B);
            proj_u_kernel<<<(U_NODES + 255) / 256, 256, 0, stream>>>(u, g_w1, A);
            edge_sorted_kernel<true, true><<<eBlocks, 256, 0, stream>>>(
                A, B, u, v, e_vals, e_src, e_dst, seid, g_w1, g_b1, g_w2, g_b2, agg);
        } else {
            edge_sorted_kernel<false, false><<<eBlocks, 256, 0, stream>>>(
                nullptr, nullptr, u, v, e_vals, e_src, e_dst, seid,
                g_w1, g_b1, g_w2, g_b2, agg);
        }
        node_kernel<<<(U_NODES + 255) / 256, 256, 0, stream>>>(
            u, agg, f_w1, f_b1, f_w2, f_b2, t_w, t_b, out);
    } else {
        float* agg0 = (float*)wsc;
        hipMemsetAsync(agg0, 0, (size_t)U_NODES * 32 * 4, stream);
        edge_direct_kernel<<<eBlocks, 256, 0, stream>>>(
            u, v, e_vals, e_src, e_dst, g_w1, g_b1, g_w2, g_b2, agg0);
        node_kernel<<<(U_NODES + 255) / 256, 256, 0, stream>>>(
            u, agg0, f_w1, f_b1, f_w2, f_b2, t_w, t_b, out);
    }
}

// Round 6
// 422.515 us; speedup vs baseline: 1.1983x; 1.1983x over previous
//
#include <hip/hip_runtime.h>
#include <cstdint>
#include <cstddef>

#define U_NODES 100000
#define V_NODES 50000
#define N_EDGES 2000000

// dims: F=32 (u), G=32 (v), H=8 (edge); g: 72->64->32 ; f: 64->64->32 ; tail 32->1
// g_w1 rows: [0,32) u-part, [32,64) v-part, [64,72) edge-val part.

typedef _Float16 f16x8 __attribute__((ext_vector_type(8)));
typedef _Float16 f16x2 __attribute__((ext_vector_type(2)));
typedef float    f32x4 __attribute__((ext_vector_type(4)));

__device__ __forceinline__ void load8f(const float* __restrict__ p, float* x) {
    const float4* p4 = reinterpret_cast<const float4*>(p);
    float4 a = p4[0], b = p4[1];
    x[0]=a.x; x[1]=a.y; x[2]=a.z; x[3]=a.w;
    x[4]=b.x; x[5]=b.y; x[6]=b.z; x[7]=b.w;
}

__device__ __forceinline__ void load32f(const float* __restrict__ p, float* x) {
    #pragma unroll
    for (int q = 0; q < 4; ++q) load8f(p + 8*q, x + 8*q);
}

// RNE round two f32 to bf16, packed low|high (fallback kernels)
__device__ __forceinline__ unsigned pack_bf16x2(float a, float b) {
    unsigned ua = __float_as_uint(a);
    ua = (ua + 0x7FFFu + ((ua >> 16) & 1u)) >> 16;
    unsigned ub = __float_as_uint(b);
    ub = (ub + 0x7FFFu + ((ub >> 16) & 1u)) & 0xFFFF0000u;
    return ua | ub;
}

// two f32 -> packed f16x2 (RNE via scalar cvt)
__device__ __forceinline__ unsigned pk16(float a, float b) {
    union { f16x2 h; unsigned u; } c;
    c.h[0] = (_Float16)a; c.h[1] = (_Float16)b;
    return c.u;
}
__device__ __forceinline__ float f16lo(unsigned w) {
    union { unsigned short u; _Float16 h; } c; c.u = (unsigned short)(w & 0xFFFFu);
    return (float)c.h;
}
__device__ __forceinline__ float f16hi(unsigned w) {
    union { unsigned short u; _Float16 h; } c; c.u = (unsigned short)(w >> 16);
    return (float)c.h;
}
__device__ __forceinline__ f16x8 as_f16x8(uint4 x) {
    union { uint4 u; f16x8 h; } c; c.u = x; return c.h;
}

// ---------------- pre-projection (A = u@W1u ; B = v@W1v + b1) ------------------

__global__ __launch_bounds__(256) void proj_u_kernel(
    const float* __restrict__ u, const float* __restrict__ g_w1,
    float* __restrict__ A)
{
    int n = blockIdx.x * 256 + threadIdx.x;
    if (n >= U_NODES) return;
    float x[32];
    load32f(u + (size_t)n * 32, x);
    float acc[64];
    #pragma unroll
    for (int j = 0; j < 64; ++j) acc[j] = 0.f;
    #pragma unroll
    for (int i = 0; i < 32; ++i) {
        #pragma unroll
        for (int j = 0; j < 64; ++j) acc[j] += x[i] * g_w1[i*64 + j];
    }
    float4* Ap = reinterpret_cast<float4*>(A + (size_t)n * 64);
    #pragma unroll
    for (int q = 0; q < 16; ++q)
        Ap[q] = make_float4(acc[4*q], acc[4*q+1], acc[4*q+2], acc[4*q+3]);
}

__global__ __launch_bounds__(256) void proj_v_kernel(
    const float* __restrict__ v, const float* __restrict__ g_w1,
    const float* __restrict__ g_b1, float* __restrict__ B)
{
    int n = blockIdx.x * 256 + threadIdx.x;
    if (n >= V_NODES) return;
    float x[32];
    load32f(v + (size_t)n * 32, x);
    float acc[64];
    #pragma unroll
    for (int j = 0; j < 64; ++j) acc[j] = g_b1[j];
    #pragma unroll
    for (int i = 0; i < 32; ++i) {
        #pragma unroll
        for (int j = 0; j < 64; ++j) acc[j] += x[i] * g_w1[(32+i)*64 + j];
    }
    float4* Bp = reinterpret_cast<float4*>(B + (size_t)n * 64);
    #pragma unroll
    for (int q = 0; q < 16; ++q)
        Bp[q] = make_float4(acc[4*q], acc[4*q+1], acc[4*q+2], acc[4*q+3]);
}

// ---------------- CSR build ----------------------------------------------------

__global__ __launch_bounds__(256) void rank_kernel(
    const int* __restrict__ e_dst, int* __restrict__ deg, int* __restrict__ rank)
{
    int e = blockIdx.x * 256 + threadIdx.x;
    if (e >= N_EDGES) return;
    rank[e] = atomicAdd(&deg[e_dst[e]], 1);
}

__global__ __launch_bounds__(256) void scan_block_kernel(
    const int* __restrict__ deg, int* __restrict__ off, int* __restrict__ aux, int n)
{
    __shared__ int s[256];
    int tid = threadIdx.x;
    int i = blockIdx.x * 256 + tid;
    int x = (i < n) ? deg[i] : 0;
    s[tid] = x;
    __syncthreads();
    #pragma unroll
    for (int o = 1; o < 256; o <<= 1) {
        int t = (tid >= o) ? s[tid - o] : 0;
        __syncthreads();
        s[tid] += t;
        __syncthreads();
    }
    if (i < n) off[i + 1] = s[tid];
    if (tid == 255) aux[blockIdx.x] = s[255];
}

__global__ __launch_bounds__(512) void scan_aux_kernel(int* __restrict__ aux, int nA)
{
    __shared__ int s[512];
    int tid = threadIdx.x;
    int x = (tid < nA) ? aux[tid] : 0;
    s[tid] = x;
    __syncthreads();
    #pragma unroll
    for (int o = 1; o < 512; o <<= 1) {
        int t = (tid >= o) ? s[tid - o] : 0;
        __syncthreads();
        s[tid] += t;
        __syncthreads();
    }
    if (tid < nA) aux[tid] = s[tid] - x;  // exclusive
}

__global__ __launch_bounds__(256) void scan_add_kernel(
    int* __restrict__ off, const int* __restrict__ aux, int n)
{
    int i = blockIdx.x * 256 + threadIdx.x;
    if (i == 0) off[0] = 0;
    if (i < n) off[i + 1] += aux[i >> 8];
}

// scatter edge id only (fallback path)
__global__ __launch_bounds__(256) void scatter_kernel(
    const int* __restrict__ e_dst, const int* __restrict__ off,
    const int* __restrict__ rank, int* __restrict__ sorted_eid)
{
    int e = blockIdx.x * 256 + threadIdx.x;
    if (e >= N_EDGES) return;
    int d = e_dst[e];
    sorted_eid[off[d] + rank[e]] = e;
}

// packed 32B edge record: [d, s, ev16 x4, pad x2] -> ONE sector touch per edge
__global__ __launch_bounds__(256) void permute_pack_kernel(
    const int* __restrict__ e_dst, const int* __restrict__ e_src,
    const int* __restrict__ rank, const int* __restrict__ off,
    const float* __restrict__ e_vals, unsigned* __restrict__ epk)
{
    int e = blockIdx.x * 256 + threadIdx.x;
    if (e >= N_EDGES) return;
    int d = e_dst[e];
    int pos = off[d] + rank[e];
    float ev[8];
    load8f(e_vals + (size_t)e * 8, ev);
    uint4 w0;
    w0.x = (unsigned)d;
    w0.y = (unsigned)e_src[e];
    w0.z = pk16(ev[0], ev[1]);
    w0.w = pk16(ev[2], ev[3]);
    uint2 w1;
    w1.x = pk16(ev[4], ev[5]);
    w1.y = pk16(ev[6], ev[7]);
    unsigned* dst = epk + (size_t)pos * 8;
    *reinterpret_cast<uint4*>(dst)     = w0;
    *reinterpret_cast<uint2*>(dst + 4) = w1;
}

// ------ edge MLP: phase-1 VALU (h1) + f16 MFMA W2 GEMM + f32 segmented reduce ---
// HAS_A: A[d] precomputed; else u-part computed from u[d] via g_w1.

template <bool HAS_A>
__global__ __launch_bounds__(256) void edge_mfma_kernel(
    const float* __restrict__ A, const float* __restrict__ B,
    const float* __restrict__ u, const unsigned* __restrict__ epk,
    const float* __restrict__ g_w1, const float* __restrict__ g_w2,
    const float* __restrict__ g_b2, float* __restrict__ agg)
{
    __shared__ unsigned s_h1[256 * 36];   // f16x2-packed h1 [edge][kp], pad 32->36
    __shared__ unsigned s_w2[32 * 33];    // f16x2-packed W2 [kp][n],   pad 32->33
    __shared__ int s_d[256];
    __shared__ int s_heads[256];          // tid | (true_head << 16)
    __shared__ int s_cnt, s_prevd, s_nextd;

    const int tid = threadIdx.x;
    const long p = (long)blockIdx.x * 256 + tid;

    if (tid == 0) {
        s_cnt = 0;
        long pprev = (long)blockIdx.x * 256 - 1;
        s_prevd = (pprev < 0) ? -2 : (int)epk[(size_t)pprev * 8];
        long pnext = (long)blockIdx.x * 256 + 256;
        s_nextd = (pnext >= N_EDGES) ? -2 : (int)epk[(size_t)pnext * 8];
    }

    // stage W2 as f16 pairs (all threads, 4 entries each)
    #pragma unroll
    for (int i = 0; i < 4; ++i) {
        int idx = tid + i * 256;          // 0..1023
        int kp = idx >> 5, n = idx & 31;
        s_w2[kp * 33 + n] = pk16(g_w2[(2*kp)*32 + n], g_w2[(2*kp+1)*32 + n]);
    }

    int d = -1;
    if (p < N_EDGES) {
        const unsigned* ep = epk + (size_t)p * 8;
        uint4 w0 = *reinterpret_cast<const uint4*>(ep);
        uint2 w1 = *reinterpret_cast<const uint2*>(ep + 4);
        d = (int)w0.x;
        int s = (int)w0.y;

        float h1[64];
        if constexpr (HAS_A) {
            const float4* Ap = reinterpret_cast<const float4*>(A + (size_t)d * 64);
            #pragma unroll
            for (int q = 0; q < 16; ++q) {
                float4 a = Ap[q];
                h1[4*q+0] = a.x; h1[4*q+1] = a.y; h1[4*q+2] = a.z; h1[4*q+3] = a.w;
            }
        } else {
            #pragma unroll
            for (int j = 0; j < 64; ++j) h1[j] = 0.f;
            float x[32];
            load32f(u + (size_t)d * 32, x);
            #pragma unroll
            for (int i = 0; i < 32; ++i) {
                #pragma unroll
                for (int j = 0; j < 64; ++j) h1[j] += x[i] * g_w1[i*64 + j];
            }
        }
        {
            const float4* Bp = reinterpret_cast<const float4*>(B + (size_t)s * 64);
            #pragma unroll
            for (int q = 0; q < 16; ++q) {
                float4 b = Bp[q];
                h1[4*q+0] += b.x; h1[4*q+1] += b.y; h1[4*q+2] += b.z; h1[4*q+3] += b.w;
            }
        }
        float ev[8];
        ev[0]=f16lo(w0.z); ev[1]=f16hi(w0.z); ev[2]=f16lo(w0.w); ev[3]=f16hi(w0.w);
        ev[4]=f16lo(w1.x); ev[5]=f16hi(w1.x); ev[6]=f16lo(w1.y); ev[7]=f16hi(w1.y);
        #pragma unroll
        for (int i = 0; i < 8; ++i) {
            #pragma unroll
            for (int j = 0; j < 64; ++j) h1[j] += ev[i] * g_w1[(64+i)*64 + j];
        }
        #pragma unroll
        for (int j = 0; j < 64; ++j) h1[j] = fmaxf(h1[j], 0.f);

        // pack to f16 pairs, write row (8x ds_write_b128)
        #pragma unroll
        for (int q = 0; q < 8; ++q) {
            uint4 w;
            w.x = pk16(h1[8*q+0], h1[8*q+1]);
            w.y = pk16(h1[8*q+2], h1[8*q+3]);
            w.z = pk16(h1[8*q+4], h1[8*q+5]);
            w.w = pk16(h1[8*q+6], h1[8*q+7]);
            *reinterpret_cast<uint4*>(&s_h1[tid*36 + 4*q]) = w;
        }
    }
    s_d[tid] = d;
    __syncthreads();

    // segment-head marking (uses s_d only)
    if (p < N_EDGES) {
        int prevd = (tid == 0) ? s_prevd : s_d[tid - 1];
        bool true_head = (prevd != d);
        bool is_head = (tid == 0) || true_head;
        if (is_head) {
            int idx = atomicAdd(&s_cnt, 1);
            s_heads[idx] = tid | (true_head ? 0x10000 : 0);
        }
    }

    // MFMA: per wave, [64 edges x 64] @ [64 x 32] via 16x mfma_f32_16x16x32_f16
    const int lane = tid & 63;
    const int wb   = (tid >> 6) * 64;
    const int lg   = lane >> 4;          // 0..3
    const int lm   = lane & 15;

    f32x4 acc[4][2];
    #pragma unroll
    for (int mt = 0; mt < 4; ++mt) {
        #pragma unroll
        for (int nt = 0; nt < 2; ++nt) {
            acc[mt][nt][0] = 0.f; acc[mt][nt][1] = 0.f;
            acc[mt][nt][2] = 0.f; acc[mt][nt][3] = 0.f;
        }
    }
    #pragma unroll
    for (int kt = 0; kt < 2; ++kt) {
        uint4 bf0, bf1;
        {
            int kp = kt*16 + lg*4;
            bf0.x = s_w2[(kp+0)*33 + lm];      bf1.x = s_w2[(kp+0)*33 + 16 + lm];
            bf0.y = s_w2[(kp+1)*33 + lm];      bf1.y = s_w2[(kp+1)*33 + 16 + lm];
            bf0.z = s_w2[(kp+2)*33 + lm];      bf1.z = s_w2[(kp+2)*33 + 16 + lm];
            bf0.w = s_w2[(kp+3)*33 + lm];      bf1.w = s_w2[(kp+3)*33 + 16 + lm];
        }
        f16x8 b0 = as_f16x8(bf0), b1 = as_f16x8(bf1);
        #pragma unroll
        for (int mt = 0; mt < 4; ++mt) {
            uint4 av = *reinterpret_cast<const uint4*>(
                &s_h1[(wb + mt*16 + lm)*36 + kt*16 + lg*4]);
            f16x8 a = as_f16x8(av);
            acc[mt][0] = __builtin_amdgcn_mfma_f32_16x16x32_f16(a, b0, acc[mt][0], 0, 0, 0);
            acc[mt][1] = __builtin_amdgcn_mfma_f32_16x16x32_f16(a, b1, acc[mt][1], 0, 0, 0);
        }
    }
    float b2a = g_b2[lm];
    float b2b = g_b2[16 + lm];
    __syncthreads();   // all MFMA LDS reads done -> safe to overwrite s_h1 with h2

    // write h2 = relu(acc + b2) as f32, D layout: row=(lane>>4)*4+reg, col=lane&15
    float* h2f = reinterpret_cast<float*>(s_h1);
    #pragma unroll
    for (int mt = 0; mt < 4; ++mt) {
        #pragma unroll
        for (int r = 0; r < 4; ++r) {
            int row = wb + mt*16 + lg*4 + r;
            h2f[row*36 + lm]      = fmaxf(acc[mt][0][r] + b2a, 0.f);
            h2f[row*36 + 16 + lm] = fmaxf(acc[mt][1][r] + b2b, 0.f);
        }
    }
    __syncthreads();

    // segmented reduce over f32 h2 (16 channel-pairs per segment)
    const int nseg = s_cnt;
    const int next_d = s_nextd;
    for (int w = tid; w < nseg * 16; w += 256) {
        int seg = w >> 4, cp = w & 15;
        int ent = s_heads[seg];
        int h = ent & 0xFFFF;
        bool thead = (ent & 0x10000) != 0;
        int dd = s_d[h];
        float s0 = 0.f, s1 = 0.f;
        int r = h;
        while (r < 256 && s_d[r] == dd) {
            s0 += h2f[r*36 + 2*cp];
            s1 += h2f[r*36 + 2*cp + 1];
            ++r;
        }
        bool end_complete = (r < 256) || (next_d != dd);
        float* dst = agg + (size_t)dd * 32 + 2 * cp;
        if (thead && end_complete) {
            *reinterpret_cast<float2*>(dst) = make_float2(s0, s1);  // sole writer
        } else {
            atomicAdd(dst + 0, s0);
            atomicAdd(dst + 1, s1);
        }
    }
}

// ------- fallback: edge MLP via seid gathers (round-4 proven path) --------------

template <bool HAS_A, bool HAS_B>
__global__ __launch_bounds__(256) void edge_sorted_kernel(
    const float* __restrict__ A, const float* __restrict__ B,
    const float* __restrict__ u, const float* __restrict__ v,
    const float* __restrict__ e_vals, const int* __restrict__ e_src,
    const int* __restrict__ e_dst, const int* __restrict__ seid,
    const float* __restrict__ g_w1, const float* __restrict__ g_b1,
    const float* __restrict__ g_w2, const float* __restrict__ g_b2,
    float* __restrict__ agg)
{
    __shared__ unsigned lds_h[256][17];
    __shared__ int lds_d[256];
    __shared__ int lds_heads[256];
    __shared__ int lds_cnt;
    __shared__ int lds_prev_d, lds_next_d;

    const int tid = threadIdx.x;
    const long p = (long)blockIdx.x * 256 + tid;

    if (tid == 0) {
        lds_cnt = 0;
        long pprev = (long)blockIdx.x * 256 - 1;
        lds_prev_d = (pprev < 0) ? -2 : e_dst[seid[pprev]];
        long pnext = (long)blockIdx.x * 256 + 256;
        lds_next_d = (pnext >= N_EDGES) ? -2 : e_dst[seid[pnext]];
    }

    int d = -1;
    if (p < N_EDGES) {
        int eid = seid[p];
        d = e_dst[eid];
        int s = e_src[eid];

        float h1[64];
        if constexpr (HAS_A) {
            const float4* Ap = reinterpret_cast<const float4*>(A + (size_t)d * 64);
            #pragma unroll
            for (int q = 0; q < 16; ++q) {
                float4 a = Ap[q];
                h1[4*q+0] = a.x; h1[4*q+1] = a.y; h1[4*q+2] = a.z; h1[4*q+3] = a.w;
            }
        } else {
            #pragma unroll
            for (int j = 0; j < 64; ++j) h1[j] = 0.f;
            float x[32];
            load32f(u + (size_t)d * 32, x);
            #pragma unroll
            for (int i = 0; i < 32; ++i) {
                #pragma unroll
                for (int j = 0; j < 64; ++j) h1[j] += x[i] * g_w1[i*64 + j];
            }
        }
        if constexpr (HAS_B) {
            const float4* Bp = reinterpret_cast<const float4*>(B + (size_t)s * 64);
            #pragma unroll
            for (int q = 0; q < 16; ++q) {
                float4 b = Bp[q];
                h1[4*q+0] += b.x; h1[4*q+1] += b.y; h1[4*q+2] += b.z; h1[4*q+3] += b.w;
            }
        } else {
            #pragma unroll
            for (int j = 0; j < 64; ++j) h1[j] += g_b1[j];
            float x[32];
            load32f(v + (size_t)s * 32, x);
            #pragma unroll
            for (int i = 0; i < 32; ++i) {
                #pragma unroll
                for (int j = 0; j < 64; ++j) h1[j] += x[i] * g_w1[(32+i)*64 + j];
            }
        }
        float ev[8];
        load8f(e_vals + (size_t)eid * 8, ev);
        #pragma unroll
        for (int i = 0; i < 8; ++i) {
            #pragma unroll
            for (int j = 0; j < 64; ++j) h1[j] += ev[i] * g_w1[(64+i)*64 + j];
        }
        #pragma unroll
        for (int j = 0; j < 64; ++j) h1[j] = fmaxf(h1[j], 0.f);

        float h2[32];
        #pragma unroll
        for (int k = 0; k < 32; ++k) h2[k] = g_b2[k];
        #pragma unroll
        for (int i = 0; i < 64; ++i) {
            #pragma unroll
            for (int k = 0; k < 32; ++k) h2[k] += h1[i] * g_w2[i*32 + k];
        }
        #pragma unroll
        for (int cp = 0; cp < 16; ++cp)
            lds_h[tid][cp] = pack_bf16x2(fmaxf(h2[2*cp], 0.f), fmaxf(h2[2*cp+1], 0.f));
    }
    lds_d[tid] = d;
    __syncthreads();

    if (p < N_EDGES) {
        int prevd = (tid == 0) ? lds_prev_d : lds_d[tid - 1];
        bool true_head = (prevd != d);
        bool is_head = (tid == 0) || true_head;
        if (is_head) {
            int idx = atomicAdd(&lds_cnt, 1);
            lds_heads[idx] = tid | (true_head ? 0x10000 : 0);
        }
    }
    __syncthreads();

    const int nseg = lds_cnt;
    const int next_d = lds_next_d;
    for (int w = tid; w < nseg * 16; w += 256) {
        int seg = w >> 4, cp = w & 15;
        int ent = lds_heads[seg];
        int h = ent & 0xFFFF;
        bool thead = (ent & 0x10000) != 0;
        int dd = lds_d[h];
        float s0 = 0.f, s1 = 0.f;
        int r = h;
        while (r < 256 && lds_d[r] == dd) {
            unsigned x = lds_h[r][cp];
            s0 += __uint_as_float(x << 16);
            s1 += __uint_as_float(x & 0xFFFF0000u);
            ++r;
        }
        bool end_complete = (r < 256) || (next_d != dd);
        float* dst = agg + (size_t)dd * 32 + 2 * cp;
        if (thead && end_complete) {
            *reinterpret_cast<float2*>(dst) = make_float2(s0, s1);
        } else {
            atomicAdd(dst + 0, s0);
            atomicAdd(dst + 1, s1);
        }
    }
}

// ---------------- node MLP (reads agg) -----------------------------------------

__global__ __launch_bounds__(256) void node_kernel(
    const float* __restrict__ u, const float* __restrict__ agg,
    const float* __restrict__ f_w1, const float* __restrict__ f_b1,
    const float* __restrict__ f_w2, const float* __restrict__ f_b2,
    const float* __restrict__ t_w, const float* __restrict__ t_b,
    float* __restrict__ out)
{
    int n = blockIdx.x * 256 + threadIdx.x;
    if (n >= U_NODES) return;
    float x[64];
    load32f(u   + (size_t)n * 32, x);
    load32f(agg + (size_t)n * 32, x + 32);
    float z1[64];
    #pragma unroll
    for (int j = 0; j < 64; ++j) z1[j] = f_b1[j];
    #pragma unroll
    for (int i = 0; i < 64; ++i) {
        #pragma unroll
        for (int j = 0; j < 64; ++j) z1[j] += x[i] * f_w1[i*64 + j];
    }
    #pragma unroll
    for (int j = 0; j < 64; ++j) z1[j] = fmaxf(z1[j], 0.f);
    float z2[32];
    #pragma unroll
    for (int k = 0; k < 32; ++k) z2[k] = f_b2[k];
    #pragma unroll
    for (int j = 0; j < 64; ++j) {
        #pragma unroll
        for (int k = 0; k < 32; ++k) z2[k] += z1[j] * f_w2[j*32 + k];
    }
    #pragma unroll
    for (int k = 0; k < 32; ++k) z2[k] = fmaxf(z2[k], 0.f);
    float o = t_b[0];
    #pragma unroll
    for (int k = 0; k < 32; ++k) o += z2[k] * t_w[k];
    out[n] = 1.f / (1.f + expf(-o));
}

// ---------------- last-resort atomic fallback -----------------------------------

__global__ __launch_bounds__(256) void edge_direct_kernel(
    const float* __restrict__ u, const float* __restrict__ v,
    const float* __restrict__ e_vals, const int* __restrict__ e_src,
    const int* __restrict__ e_dst, const float* __restrict__ g_w1,
    const float* __restrict__ g_b1, const float* __restrict__ g_w2,
    const float* __restrict__ g_b2, float* __restrict__ agg)
{
    int e = blockIdx.x * 256 + threadIdx.x;
    if (e >= N_EDGES) return;
    int d = e_dst[e];
    int s = e_src[e];
    float x[72];
    load32f(u + (size_t)d * 32, x);
    load32f(v + (size_t)s * 32, x + 32);
    load8f(e_vals + (size_t)e * 8, x + 64);
    float h1[64];
    #pragma unroll
    for (int j = 0; j < 64; ++j) h1[j] = g_b1[j];
    #pragma unroll
    for (int i = 0; i < 72; ++i) {
        #pragma unroll
        for (int j = 0; j < 64; ++j) h1[j] += x[i] * g_w1[i*64 + j];
    }
    #pragma unroll
    for (int j = 0; j < 64; ++j) h1[j] = fmaxf(h1[j], 0.f);
    float acc2[32];
    #pragma unroll
    for (int k = 0; k < 32; ++k) acc2[k] = g_b2[k];
    #pragma unroll
    for (int i = 0; i < 64; ++i) {
        #pragma unroll
        for (int k = 0; k < 32; ++k) acc2[k] += h1[i] * g_w2[i*32 + k];
    }
    float* aggp = agg + (size_t)d * 32;
    #pragma unroll
    for (int k = 0; k < 32; ++k) atomicAdd(aggp + k, fmaxf(acc2[k], 0.f));
}

// ---------------- launch -------------------------------------------------------

static inline size_t align256(size_t x) { return (x + 255) & ~(size_t)255; }

extern "C" void kernel_launch(void* const* d_in, const int* in_sizes, int n_in,
                              void* d_out, int out_size, void* d_ws, size_t ws_size,
                              hipStream_t stream) {
    const float* u      = (const float*)d_in[0];
    const float* v      = (const float*)d_in[1];
    const float* e_vals = (const float*)d_in[2];
    const int*   e_src  = (const int*)  d_in[3];
    const int*   e_dst  = (const int*)  d_in[4];
    const float* g_w1   = (const float*)d_in[5];
    const float* g_b1   = (const float*)d_in[6];
    const float* g_w2   = (const float*)d_in[7];
    const float* g_b2   = (const float*)d_in[8];
    const float* f_w1   = (const float*)d_in[9];
    const float* f_b1   = (const float*)d_in[10];
    const float* f_w2   = (const float*)d_in[11];
    const float* f_b2   = (const float*)d_in[12];
    const float* t_w    = (const float*)d_in[13];
    const float* t_b    = (const float*)d_in[14];
    float* out = (float*)d_out;

    char* wsc = (char*)d_ws;
    const int nChunks = (U_NODES + 255) / 256;                    // 391
    const int eBlocks = (N_EDGES + 255) / 256;

    const size_t degB  = align256((size_t)U_NODES * 4);
    const size_t offB  = align256((size_t)(U_NODES + 1) * 4);
    const size_t auxB  = align256((size_t)nChunks * 4);
    const size_t aggB  = align256((size_t)U_NODES * 32 * 4);      // 12.8 MB
    const size_t e4B   = align256((size_t)N_EDGES * 4);           // 8 MB
    const size_t epkB  = align256((size_t)N_EDGES * 32);          // 64 MB packed records
    const size_t bB    = align256((size_t)V_NODES * 64 * 4);      // 12.8 MB
    const size_t aB    = align256((size_t)U_NODES * 64 * 4);      // 25.6 MB

    size_t o = 0;
    size_t oDeg = o; o += degB;
    size_t oOff = o; o += offB;
    size_t oAux = o; o += auxB;
    size_t oAgg = o; o += aggB;
    size_t baseNeed = o;                                          // ~13.7 MB

    // MFMA-path layout
    size_t oEp = o;  o += epkB;
    size_t oBn = o;  o += bB;
    size_t needT2r = o + e4B;          // B + separate rank (~98.5 MB)
    size_t oAn = o;  o += aB;
    size_t needT1 = o;                 // ~116 MB ; rank aliases A (proj_u after permute)

    // fallback (round-4) layout
    size_t o3 = baseNeed;
    size_t oSeid = o3; o3 += e4B;
    size_t needT4 = o3 + e4B;          // <false,false> : rank after seid (~29.7 MB)
    size_t oB3 = o3;   o3 += bB;
    size_t oA3 = o3;   o3 += aB;
    size_t needT3 = o3;                // ~60 MB ; rank aliases A3

    int* deg   = (int*)(wsc + oDeg);
    int* off   = (int*)(wsc + oOff);
    int* aux   = (int*)(wsc + oAux);
    float* agg = (float*)(wsc + oAgg);

    if (ws_size >= needT2r) {
        const bool hasA = (ws_size >= needT1);
        unsigned* epk = (unsigned*)(wsc + oEp);
        float* B   = (float*)(wsc + oBn);
        float* A   = hasA ? (float*)(wsc + oAn) : nullptr;
        int* rank  = hasA ? (int*)A : (int*)(wsc + oAn);  // tier2: own 8MB past B

        hipMemsetAsync(deg, 0, (size_t)U_NODES * 4, stream);
        hipMemsetAsync(agg, 0, (size_t)U_NODES * 32 * 4, stream);

        rank_kernel<<<eBlocks, 256, 0, stream>>>(e_dst, deg, rank);
        scan_block_kernel<<<nChunks, 256, 0, stream>>>(deg, off, aux, U_NODES);
        scan_aux_kernel<<<1, 512, 0, stream>>>(aux, nChunks);
        scan_add_kernel<<<nChunks, 256, 0, stream>>>(off, aux, U_NODES);
        permute_pack_kernel<<<eBlocks, 256, 0, stream>>>(e_dst, e_src, rank, off,
                                                         e_vals, epk);
        proj_v_kernel<<<(V_NODES + 255) / 256, 256, 0, stream>>>(v, g_w1, g_b1, B);
        if (hasA) {
            proj_u_kernel<<<(U_NODES + 255) / 256, 256, 0, stream>>>(u, g_w1, A);
            edge_mfma_kernel<true><<<eBlocks, 256, 0, stream>>>(
                A, B, u, epk, g_w1, g_w2, g_b2, agg);
        } else {
            edge_mfma_kernel<false><<<eBlocks, 256, 0, stream>>>(
                nullptr, B, u, epk, g_w1, g_w2, g_b2, agg);
        }
        node_kernel<<<(U_NODES + 255) / 256, 256, 0, stream>>>(
            u, agg, f_w1, f_b1, f_w2, f_b2, t_w, t_b, out);
    } else if (ws_size >= needT4) {
        const bool hasAB = (ws_size >= needT3);
        int* seid = (int*)(wsc + oSeid);
        float* B = hasAB ? (float*)(wsc + oB3) : nullptr;
        float* A = hasAB ? (float*)(wsc + oA3) : nullptr;
        int* rank = hasAB ? (int*)A : (int*)(wsc + oSeid + e4B);

        hipMemsetAsync(deg, 0, (size_t)U_NODES * 4, stream);
        hipMemsetAsync(agg, 0, (size_t)U_NODES * 32 * 4, stream);

        rank_kernel<<<eBlocks, 256, 0, stream>>>(e_dst, deg, rank);
        scan_block_kernel<<<nChunks, 256, 0, stream>>>(deg, off, aux, U_NODES);
        scan_aux_kernel<<<1, 512, 0, stream>>>(aux, nChunks);
        scan_add_kernel<<<nChunks, 256, 0, stream>>>(off, aux, U_NODES);
        scatter_kernel<<<eBlocks, 256, 0, stream>>>(e_dst, off, rank, seid);

        if (hasAB) {
            proj_v_kernel<<<(V_NODES + 255) / 256, 256, 0, stream>>>(v, g_w1, g_b1, B);
            proj_u_kernel<<<(U_NODES + 255) / 256, 256, 0, stream>>>(u, g_w1, A);
            edge_sorted_kernel<true, true><<<eBlocks, 256, 0, stream>>>(
                A, B, u, v, e_vals, e_src, e_dst, seid, g_w1, g_b1, g_w2, g_b2, agg);
        } else {
            edge_sorted_kernel<false, false><<<eBlocks, 256, 0, stream>>>(
                nullptr, nullptr, u, v, e_vals, e_src, e_dst, seid,
                g_w1, g_b1, g_w2, g_b2, agg);
        }
        node_kernel<<<(U_NODES + 255) / 256, 256, 0, stream>>>(
            u, agg, f_w1, f_b1, f_w2, f_b2, t_w, t_b, out);
    } else {
        float* agg0 = (float*)wsc;
        hipMemsetAsync(agg0, 0, (size_t)U_NODES * 32 * 4, stream);
        edge_direct_kernel<<<eBlocks, 256, 0, stream>>>(
            u, v, e_vals, e_src, e_dst, g_w1, g_b1, g_w2, g_b2, agg0);
        node_kernel<<<(U_NODES + 255) / 256, 256, 0, stream>>>(
            u, agg0, f_w1, f_b1, f_w2, f_b2, t_w, t_b, out);
    }
}